// Round 11
// baseline (434.441 us; speedup 1.0000x reference)
//
#include <hip/hip_runtime.h>
#include <hip/hip_fp16.h>
#include <math.h>

#define KK 25
#define H1C 32
#define H2C 64
#define FCC 128
#define NCLS 10
#define NG 64
#define M1 32      // nodes per block, layer-1
#define M2 16      // nodes per block, layer-2
#define NHB 256    // histogram/bucket blocks (fill all CUs)
#define HBIN 10240 // LDS histogram bins per pass (40 KB)
#define ECH2 256   // staged edges per chunk, l2

typedef _Float16 v8h __attribute__((ext_vector_type(8)));
typedef float v4f __attribute__((ext_vector_type(4)));

// Native FP atomic add (ds_add_f32 / global_atomic_add_f32). Plain atomicAdd
// on float lowers to a CAS retry loop without -munsafe-fp-atomics — measured
// ~3x kernel-level slowdown in R4/R5/R9/R10 and 135us in R7's deg_cnt.
__device__ __forceinline__ void atomAddF(float* p, float v) {
    unsafeAtomicAdd(p, v);
}

// ---------------- degree histogram: per-block LDS bins, int atomics ----------
__global__ __launch_bounds__(256) void hist_kernel(
    const int* __restrict__ edge_index, int E, int N,
    int* __restrict__ part) {            // [NHB][N]
    __shared__ int hs[HBIN];
    int b = blockIdx.x, tid = threadIdx.x;
    int per = (E + NHB - 1) / NHB;
    int beg = b * per, end = min(E, beg + per);
    for (int lo = 0; lo < N; lo += HBIN) {
        int sz = min(HBIN, N - lo);
        __syncthreads();
        for (int i = tid; i < sz; i += 256) hs[i] = 0;
        __syncthreads();
        for (int i = beg + tid; i < end; i += 256) {
            int d = edge_index[E + i] - lo;
            if ((unsigned)d < (unsigned)sz) atomicAdd(&hs[d], 1);   // int ds_add
        }
        __syncthreads();
        for (int i = tid; i < sz; i += 256) part[(size_t)b * N + lo + i] = hs[i];
    }
}

__global__ void merge_kernel(const int* __restrict__ part, int N,
                             int* __restrict__ degi) {
    int n = blockIdx.x * 256 + threadIdx.x;
    if (n >= N) return;
    int s = 0;
#pragma unroll 8
    for (int b = 0; b < NHB; b++) s += part[(size_t)b * N + n];
    degi[n] = s;
}

// ---------------- prefix-sum (3-kernel) over degi -> rowst ----------------
__global__ void scan1_kernel(const int* __restrict__ degi, int N,
                             int* __restrict__ incl, int* __restrict__ bsum) {
    __shared__ int s[256];
    int tid = threadIdx.x;
    int i = blockIdx.x * 256 + tid;
    int v = (i < N) ? degi[i] : 0;
    s[tid] = v;
    __syncthreads();
    for (int off = 1; off < 256; off <<= 1) {
        int t = (tid >= off) ? s[tid - off] : 0;
        __syncthreads();
        s[tid] += t;
        __syncthreads();
    }
    if (i < N) incl[i] = s[tid];
    if (tid == 255) bsum[blockIdx.x] = s[255];
}

__global__ void scan2_kernel(int* __restrict__ bsum, int nb) {
    __shared__ int s[256];
    int tid = threadIdx.x;
    int v = (tid < nb) ? bsum[tid] : 0;
    s[tid] = v;
    __syncthreads();
    for (int off = 1; off < 256; off <<= 1) {
        int t = (tid >= off) ? s[tid - off] : 0;
        __syncthreads();
        s[tid] += t;
        __syncthreads();
    }
    if (tid < nb) bsum[tid] = s[tid] - v;   // exclusive
}

__global__ void scan3_kernel(const int* __restrict__ incl, const int* __restrict__ degi,
                             const int* __restrict__ bsum, int N,
                             int* __restrict__ rowst) {
    int i = blockIdx.x * 256 + threadIdx.x;
    if (i >= N) return;
    rowst[i] = incl[i] - degi[i] + bsum[blockIdx.x];
}

// ---------------- offsets: part[b][n] <- rowst[n] + sum_{b'<b} part[b'][n] ----
__global__ void offs_kernel(const int* __restrict__ rowst, int N,
                            int* __restrict__ part) {
    int n = blockIdx.x * 256 + threadIdx.x;
    if (n >= N) return;
    int run = rowst[n];
#pragma unroll 8
    for (int b = 0; b < NHB; b++) {
        int t = part[(size_t)b * N + n];
        part[(size_t)b * N + n] = run;
        run += t;
    }
}

// ---------------- bucket pass 2: place edges via LDS rank counters ----------
__global__ __launch_bounds__(256) void bucket2_kernel(
    const float* __restrict__ edge_attr, const int* __restrict__ edge_index,
    int E, int N, int* __restrict__ part, int4* __restrict__ es) {
    __shared__ int hs[HBIN];
    int b = blockIdx.x, tid = threadIdx.x;
    int per = (E + NHB - 1) / NHB;
    int beg = b * per, end = min(E, beg + per);
    for (int lo = 0; lo < N; lo += HBIN) {
        int sz = min(HBIN, N - lo);
        __syncthreads();
        for (int i = tid; i < sz; i += 256) hs[i] = part[(size_t)b * N + lo + i];
        __syncthreads();
        for (int e = beg + tid; e < end; e += 256) {
            int dst = edge_index[E + e];
            int d = dst - lo;
            if ((unsigned)d < (unsigned)sz) {
                int pos = atomicAdd(&hs[d], 1);          // int ds_add_rtn: rank
                float v0 = edge_attr[2 * e + 0] * 4.0f;
                float v1 = edge_attr[2 * e + 1] * 4.0f;
                int k0 = min(max((int)floorf(v0), 0), 3);
                int k1 = min(max((int)floorf(v1), 0), 3);
                float f0 = v0 - (float)k0, f1 = v1 - (float)k1;
                es[pos] = make_int4(edge_index[e], (dst << 8) | (k0 + 5 * k1),
                                    __float_as_int(f0), __float_as_int(f1));
            }
        }
    }
}

// ---------------- W2 -> fp16 transposed [25][64][32] (c innermost) ----------
__global__ void w2t_kernel(const float* __restrict__ W2, __half* __restrict__ W2t) {
    int idx = blockIdx.x * 256 + threadIdx.x;
    if (idx >= KK * H2C * H1C) return;
    int c = idx & 31, o = (idx >> 5) & 63, k = idx >> 11;
    W2t[idx] = __float2half(W2[(k * H1C + c) * H2C + o]);
}

// ---------------- layer 1: CSR gather, register accumulate (R8 known-good) --
__global__ __launch_bounds__(256) void l1_kernel(
    const float* __restrict__ x,
    const int* __restrict__ rowst, const int* __restrict__ degi,
    const int4* __restrict__ es,
    const float* __restrict__ W1, const float* __restrict__ root1,
    const float* __restrict__ b1, int N, int E,
    float* __restrict__ h1, __half* __restrict__ h1f) {
    __shared__ float w1s[KK * H1C];
    __shared__ float agg1[M1 * H1C];
    __shared__ int4 eb[8][32];
    __shared__ float xb[8][32];
    int tid = threadIdx.x;
    for (int i = tid; i < KK * H1C; i += 256) w1s[i] = W1[i];
    for (int i = tid; i < M1 * H1C; i += 256) agg1[i] = 0.0f;
    __syncthreads();
    int g = tid >> 5, o = tid & 31;
    int n0 = blockIdx.x * M1;
    int blkBeg = rowst[n0];
    int blkEnd = (n0 + M1 < N) ? rowst[n0 + M1] : E;
    int total = blkEnd - blkBeg;
    int per = (total + 7) >> 3;
    int wBeg = blkBeg + g * per;
    int wEnd = min(blkEnd, wBeg + per);
    int curDst = -1;
    float acc = 0.0f;
    for (int base = wBeg; base < wEnd; base += 32) {
        int m = min(32, wEnd - base);
        if (o < m) {
            int4 ed = es[base + o];
            eb[g][o] = ed;
            xb[g][o] = x[ed.x];
        }
        for (int jj = 0; jj < m; jj++) {
            int4 ed = eb[g][jj];
            float xs = xb[g][jj];
            int dst = ed.y >> 8;
            if (dst != curDst) {
                if (curDst >= 0) atomAddF(&agg1[(curDst - n0) * H1C + o], acc);
                acc = 0.0f;
                curDst = dst;
            }
            float f0 = __int_as_float(ed.z), f1 = __int_as_float(ed.w);
            float g0 = 1.0f - f0, g1 = 1.0f - f1;
            int kb = (ed.y & 0xff) << 5;
            float coef = g0 * g1 * w1s[kb + o] + f0 * g1 * w1s[kb + 32 + o] +
                         g0 * f1 * w1s[kb + 160 + o] + f0 * f1 * w1s[kb + 192 + o];
            acc = fmaf(xs, coef, acc);
        }
    }
    if (curDst >= 0) atomAddF(&agg1[(curDst - n0) * H1C + o], acc);
    __syncthreads();
#pragma unroll
    for (int i = 0; i < 4; i++) {
        int ln = g + 8 * i;
        int n = n0 + ln;
        if (n < N) {
            float rdeg = 1.0f / fmaxf((float)degi[n], 1.0f);
            float hv = fmaxf(agg1[ln * H1C + o] * rdeg + x[n] * root1[o] + b1[o], 0.0f);
            h1[n * H1C + o] = hv;
            h1f[n * H1C + o] = __float2half(hv);
        }
    }
}

// ---------------- xW2 via MFMA: [N][25][64] fp16 = h1f @ W2t ----------------
__global__ __launch_bounds__(256) void xw2m_kernel(
    const __half* __restrict__ h1f,   // [N][32]
    const __half* __restrict__ W2t,   // [25][64][32] (c innermost)
    int N, __half* __restrict__ xph) {  // [N][25][64]
    int wv = threadIdx.x >> 6;
    int lane = threadIdx.x & 63;
    int r15 = lane & 15, quad = lane >> 4;
    int n0 = blockIdx.x * 16;
    int o0 = wv * 16;
    v8h afrag = {};
    int an = n0 + r15;
    if (an < N) afrag = *(const v8h*)(h1f + (size_t)an * H1C + quad * 8);
    for (int k = 0; k < KK; k++) {
        v8h bfrag = *(const v8h*)(W2t + ((k << 6) + o0 + r15) * H1C + quad * 8);
        v4f acc = {};
        acc = __builtin_amdgcn_mfma_f32_16x16x32_f16(afrag, bfrag, acc, 0, 0, 0);
#pragma unroll
        for (int r = 0; r < 4; r++) {
            int mn = n0 + quad * 4 + r;
            if (mn < N)
                xph[(size_t)mn * (KK * H2C) + (k << 6) + o0 + r15] = __float2half(acc[r]);
        }
    }
}

// ---------------- layer 2: branchless all-tap gather, 4-edge load batches ----
// 256 thr = 4 waves; wave = one edge per slot: lane>>5 = tap row half, lane&31 = ch-pair.
__global__ __launch_bounds__(256) void l2_kernel(
    const float* __restrict__ h1,
    const int* __restrict__ rowst, const int* __restrict__ degi,
    const int4* __restrict__ es,
    const unsigned* __restrict__ xphu,  // [N][25][32] uints (=2 halves)
    const float* __restrict__ root2, const float* __restrict__ b2,
    const int* __restrict__ batch,
    int N, int E, float* __restrict__ gsum) {
    __shared__ float agg[M2 * H2C];   // 4 KB (reused as h2buf)
    __shared__ int4 eb[ECH2];         // 4 KB
    int tid = threadIdx.x;
    for (int i = tid; i < M2 * H2C; i += 256) agg[i] = 0.0f;
    int w = tid >> 6, lane = tid & 63;
    int j = lane >> 5, o2 = lane & 31;
    int n0 = blockIdx.x * M2;
    int blkBeg = rowst[n0];
    int blkEnd = (n0 + M2 < N) ? rowst[n0 + M2] : E;
    for (int base = blkBeg; base < blkEnd; base += ECH2) {
        int m = min(ECH2, blkEnd - base);
        __syncthreads();
        for (int i = tid; i < m; i += 256) eb[i] = es[base + i];
        __syncthreads();
        for (int i = w; i < m; i += 16) {      // batch: edges i, i+4, i+8, i+12
            int4 ed[4];
            unsigned ta[4], tb[4];
            bool act[4];
#pragma unroll
            for (int t = 0; t < 4; t++) {      // issue all 8 loads first
                int ii = i + 4 * t;
                act[t] = ii < m;
                ed[t] = eb[act[t] ? ii : i];
                const unsigned* p = xphu + (size_t)ed[t].x * 800 +
                                    ((ed[t].y & 0xff) << 5) + lane;
                ta[t] = p[0];     // tap rows kbase / kbase+1 (by lane half)
                tb[t] = p[160];   // tap rows kbase+5 / kbase+6
            }
#pragma unroll
            for (int t = 0; t < 4; t++) {      // consume
                if (act[t]) {
                    float f0 = __int_as_float(ed[t].z), f1 = __int_as_float(ed[t].w);
                    float blo = j ? f0 : (1.0f - f0);
                    float g1v = 1.0f - f1;
                    __half2 hA = *(__half2*)&ta[t], hB = *(__half2*)&tb[t];
                    float vx = blo * fmaf(g1v, __low2float(hA), f1 * __low2float(hB));
                    float vy = blo * fmaf(g1v, __high2float(hA), f1 * __high2float(hB));
                    int dl = (ed[t].y >> 8) - n0;
                    atomAddF(&agg[dl * H2C + 2 * o2], vx);
                    atomAddF(&agg[dl * H2C + 2 * o2 + 1], vy);
                }
            }
        }
    }
    __syncthreads();

    // epilogue: h2 = relu(agg/deg + h1@root2 + b2), in place in agg
#pragma unroll
    for (int i = 0; i < 4; i++) {
        int ln = w + 4 * i;
        int n = n0 + ln;
        if (n < N) {
            float rd = 1.0f / fmaxf((float)degi[n], 1.0f);
            float v = agg[ln * H2C + lane] * rd + b2[lane];
            const float* hr = h1 + n * H1C;
#pragma unroll 8
            for (int c = 0; c < H1C; c++) v = fmaf(hr[c], root2[c * H2C + lane], v);
            agg[ln * H2C + lane] = fmaxf(v, 0.0f);
        } else {
            agg[ln * H2C + lane] = 0.0f;
        }
    }
    __syncthreads();

    // pool: one atomic per (graph,o) per block
    if (tid < H2C) {
        float run = 0.0f;
        int curg = batch[n0];
        for (int ln = 0; ln < M2; ln++) {
            int n = n0 + ln;
            if (n >= N) break;
            int gg = batch[n];
            if (gg != curg) {
                atomAddF(&gsum[curg * H2C + tid], run);
                run = 0.0f;
                curg = gg;
            }
            run += agg[ln * H2C + tid];
        }
        atomAddF(&gsum[curg * H2C + tid], run);
    }
}

// ---------------- head: count via binary search, FC1+relu, FC2, log_softmax --
__global__ void head_kernel(const float* __restrict__ gsum,
                            const int* __restrict__ batch, int N,
                            const float* __restrict__ Wf1, const float* __restrict__ bf1,
                            const float* __restrict__ Wf2, const float* __restrict__ bf2,
                            float* __restrict__ out) {
    __shared__ float gc[H2C];
    __shared__ float t1[FCC];
    __shared__ float lg[NCLS];
    __shared__ float lse;
    __shared__ float scnt;
    int g = blockIdx.x, tid = threadIdx.x;
    if (tid == 0) {
        int lo = 0, hi = N;
        while (lo < hi) { int m = (lo + hi) >> 1; if (batch[m] < g) lo = m + 1; else hi = m; }
        int lb = lo;
        lo = 0; hi = N;
        while (lo < hi) { int m = (lo + hi) >> 1; if (batch[m] <= g) lo = m + 1; else hi = m; }
        scnt = (float)(lo - lb);
    }
    __syncthreads();
    if (tid < H2C) gc[tid] = gsum[g * H2C + tid] / fmaxf(scnt, 1.0f);
    __syncthreads();
    {
        float acc = bf1[tid];
        for (int c = 0; c < H2C; c++) acc += gc[c] * Wf1[c * FCC + tid];
        t1[tid] = fmaxf(acc, 0.0f);
    }
    __syncthreads();
    if (tid < NCLS) {
        float acc = bf2[tid];
        for (int jj = 0; jj < FCC; jj++) acc += t1[jj] * Wf2[jj * NCLS + tid];
        lg[tid] = acc;
    }
    __syncthreads();
    if (tid == 0) {
        float m = lg[0];
        for (int c = 1; c < NCLS; c++) m = fmaxf(m, lg[c]);
        float s = 0.0f;
        for (int c = 0; c < NCLS; c++) s += expf(lg[c] - m);
        lse = m + logf(s);
    }
    __syncthreads();
    if (tid < NCLS) out[g * NCLS + tid] = lg[tid] - lse;
}

extern "C" void kernel_launch(void* const* d_in, const int* in_sizes, int n_in,
                              void* d_out, int out_size, void* d_ws, size_t ws_size,
                              hipStream_t stream) {
    const float* x          = (const float*)d_in[0];
    const float* edge_attr  = (const float*)d_in[1];
    const float* W1         = (const float*)d_in[2];
    const float* root1      = (const float*)d_in[3];
    const float* b1         = (const float*)d_in[4];
    const float* W2         = (const float*)d_in[5];
    const float* root2      = (const float*)d_in[6];
    const float* b2         = (const float*)d_in[7];
    const float* Wf1        = (const float*)d_in[8];
    const float* bf1        = (const float*)d_in[9];
    const float* Wf2        = (const float*)d_in[10];
    const float* bf2        = (const float*)d_in[11];
    const int*   edge_index = (const int*)d_in[12];
    const int*   batch      = (const int*)d_in[13];
    float* out = (float*)d_out;

    const int N = in_sizes[13];       // 20000
    const int E = in_sizes[12] / 2;   // 320000
    const int NB = (N + 255) / 256;   // scan blocks

    // -------- workspace layout --------
    int4*     es   = (int4*)d_ws;                        // E packed sorted edges
    unsigned* xphu = (unsigned*)(es + E);                // N*800 uints = fp16 [N][25][64]
    __half*   w2t  = (__half*)(xphu + (size_t)N * 800);  // 25*64*32 halves
    __half*   h1f  = w2t + KK * H2C * H1C;               // N*32 halves
    float* gsum  = (float*)(h1f + (size_t)N * H1C);      // NG*H2C  -- zeroed
    int*   degi  = (int*)(gsum + NG * H2C);              // N
    int*   rowst = degi + N;                             // N
    int*   incl  = rowst + N;                            // N
    int*   bsum  = incl + N;                             // 256
    float* h1    = (float*)(bsum + 256);                 // N*H1C
    int*   part  = (int*)(h1 + (size_t)N * H1C);         // NHB*N (20.5 MB)

    hipMemsetAsync(gsum, 0, (size_t)NG * H2C * sizeof(float), stream);

    hist_kernel<<<NHB, 256, 0, stream>>>(edge_index, E, N, part);
    merge_kernel<<<NB, 256, 0, stream>>>(part, N, degi);

    scan1_kernel<<<NB, 256, 0, stream>>>(degi, N, incl, bsum);
    scan2_kernel<<<1, 256, 0, stream>>>(bsum, NB);
    scan3_kernel<<<NB, 256, 0, stream>>>(incl, degi, bsum, N, rowst);

    offs_kernel<<<NB, 256, 0, stream>>>(rowst, N, part);
    bucket2_kernel<<<NHB, 256, 0, stream>>>(edge_attr, edge_index, E, N, part, es);

    w2t_kernel<<<(KK * H2C * H1C + 255) / 256, 256, 0, stream>>>(W2, w2t);

    l1_kernel<<<(N + M1 - 1) / M1, 256, 0, stream>>>(
        x, rowst, degi, es, W1, root1, b1, N, E, h1, h1f);

    xw2m_kernel<<<(N + 15) / 16, 256, 0, stream>>>(h1f, w2t, N, (__half*)xphu);

    l2_kernel<<<(N + M2 - 1) / M2, 256, 0, stream>>>(
        h1, rowst, degi, es, xphu, root2, b2, batch, N, E, gsum);

    head_kernel<<<NG, FCC, 0, stream>>>(gsum, batch, N, Wf1, bf1, Wf2, bf2, out);
}

// Round 12
// 358.024 us; speedup vs baseline: 1.2134x; 1.2134x over previous
//
#include <hip/hip_runtime.h>
#include <hip/hip_fp16.h>
#include <math.h>

#define KK 25
#define H1C 32
#define H2C 64
#define FCC 128
#define NCLS 10
#define NG 64
#define M1 32      // nodes per block, layer-1
#define M2 16      // nodes per block, fin2
#define NHB 256    // histogram/bucket blocks
#define HBIN 10240 // LDS histogram bins per pass (40 KB)

typedef _Float16 v8h __attribute__((ext_vector_type(8)));
typedef float v4f __attribute__((ext_vector_type(4)));

__device__ __forceinline__ void atomAddF(float* p, float v) {
    unsafeAtomicAdd(p, v);   // native global_atomic_add_f32
}

// ---------------- degree histogram: per-block LDS bins, int atomics ----------
__global__ __launch_bounds__(256) void hist_kernel(
    const int* __restrict__ edge_index, int E, int N,
    int* __restrict__ part) {            // [NHB][N]
    __shared__ int hs[HBIN];
    int b = blockIdx.x, tid = threadIdx.x;
    int per = (E + NHB - 1) / NHB;
    int beg = b * per, end = min(E, beg + per);
    for (int lo = 0; lo < N; lo += HBIN) {
        int sz = min(HBIN, N - lo);
        __syncthreads();
        for (int i = tid; i < sz; i += 256) hs[i] = 0;
        __syncthreads();
        for (int i = beg + tid; i < end; i += 256) {
            int d = edge_index[E + i] - lo;
            if ((unsigned)d < (unsigned)sz) atomicAdd(&hs[d], 1);
        }
        __syncthreads();
        for (int i = tid; i < sz; i += 256) part[(size_t)b * N + lo + i] = hs[i];
    }
}

__global__ void merge_kernel(const int* __restrict__ part, int N,
                             int* __restrict__ degi) {
    int n = blockIdx.x * 256 + threadIdx.x;
    if (n >= N) return;
    int s = 0;
#pragma unroll 8
    for (int b = 0; b < NHB; b++) s += part[(size_t)b * N + n];
    degi[n] = s;
}

// ---------------- prefix-sum (3-kernel) over degi -> rowst ----------------
__global__ void scan1_kernel(const int* __restrict__ degi, int N,
                             int* __restrict__ incl, int* __restrict__ bsum) {
    __shared__ int s[256];
    int tid = threadIdx.x;
    int i = blockIdx.x * 256 + tid;
    int v = (i < N) ? degi[i] : 0;
    s[tid] = v;
    __syncthreads();
    for (int off = 1; off < 256; off <<= 1) {
        int t = (tid >= off) ? s[tid - off] : 0;
        __syncthreads();
        s[tid] += t;
        __syncthreads();
    }
    if (i < N) incl[i] = s[tid];
    if (tid == 255) bsum[blockIdx.x] = s[255];
}

__global__ void scan2_kernel(int* __restrict__ bsum, int nb) {
    __shared__ int s[256];
    int tid = threadIdx.x;
    int v = (tid < nb) ? bsum[tid] : 0;
    s[tid] = v;
    __syncthreads();
    for (int off = 1; off < 256; off <<= 1) {
        int t = (tid >= off) ? s[tid - off] : 0;
        __syncthreads();
        s[tid] += t;
        __syncthreads();
    }
    if (tid < nb) bsum[tid] = s[tid] - v;   // exclusive
}

__global__ void scan3_kernel(const int* __restrict__ incl, const int* __restrict__ degi,
                             const int* __restrict__ bsum, int N,
                             int* __restrict__ rowst) {
    int i = blockIdx.x * 256 + threadIdx.x;
    if (i >= N) return;
    rowst[i] = incl[i] - degi[i] + bsum[blockIdx.x];
}

// ---------------- offsets: part[b][n] <- rowst[n] + sum_{b'<b} part[b'][n] ----
__global__ void offs_kernel(const int* __restrict__ rowst, int N,
                            int* __restrict__ part) {
    int n = blockIdx.x * 256 + threadIdx.x;
    if (n >= N) return;
    int run = rowst[n];
#pragma unroll 8
    for (int b = 0; b < NHB; b++) {
        int t = part[(size_t)b * N + n];
        part[(size_t)b * N + n] = run;
        run += t;
    }
}

// ---------------- bucket pass 2: place edges via LDS rank counters ----------
__global__ __launch_bounds__(256) void bucket2_kernel(
    const float* __restrict__ edge_attr, const int* __restrict__ edge_index,
    int E, int N, int* __restrict__ part, int4* __restrict__ es) {
    __shared__ int hs[HBIN];
    int b = blockIdx.x, tid = threadIdx.x;
    int per = (E + NHB - 1) / NHB;
    int beg = b * per, end = min(E, beg + per);
    for (int lo = 0; lo < N; lo += HBIN) {
        int sz = min(HBIN, N - lo);
        __syncthreads();
        for (int i = tid; i < sz; i += 256) hs[i] = part[(size_t)b * N + lo + i];
        __syncthreads();
        for (int e = beg + tid; e < end; e += 256) {
            int dst = edge_index[E + e];
            int d = dst - lo;
            if ((unsigned)d < (unsigned)sz) {
                int pos = atomicAdd(&hs[d], 1);          // int ds_add_rtn: rank
                float v0 = edge_attr[2 * e + 0] * 4.0f;
                float v1 = edge_attr[2 * e + 1] * 4.0f;
                int k0 = min(max((int)floorf(v0), 0), 3);
                int k1 = min(max((int)floorf(v1), 0), 3);
                float f0 = v0 - (float)k0, f1 = v1 - (float)k1;
                es[pos] = make_int4(edge_index[e], (dst << 8) | (k0 + 5 * k1),
                                    __float_as_int(f0), __float_as_int(f1));
            }
        }
    }
}

// ---------------- W2 -> fp16 transposed [25][64][32] (c innermost) ----------
__global__ void w2t_kernel(const float* __restrict__ W2, __half* __restrict__ W2t) {
    int idx = blockIdx.x * 256 + threadIdx.x;
    if (idx >= KK * H2C * H1C) return;
    int c = idx & 31, o = (idx >> 5) & 63, k = idx >> 11;
    W2t[idx] = __float2half(W2[(k * H1C + c) * H2C + o]);
}

// ---------------- layer 1: CSR gather, register accumulate (R8 known-good) --
__global__ __launch_bounds__(256) void l1_kernel(
    const float* __restrict__ x,
    const int* __restrict__ rowst, const int* __restrict__ degi,
    const int4* __restrict__ es,
    const float* __restrict__ W1, const float* __restrict__ root1,
    const float* __restrict__ b1, int N, int E,
    float* __restrict__ h1, __half* __restrict__ h1f) {
    __shared__ float w1s[KK * H1C];
    __shared__ float agg1[M1 * H1C];
    __shared__ int4 eb[8][32];
    __shared__ float xb[8][32];
    int tid = threadIdx.x;
    for (int i = tid; i < KK * H1C; i += 256) w1s[i] = W1[i];
    for (int i = tid; i < M1 * H1C; i += 256) agg1[i] = 0.0f;
    __syncthreads();
    int g = tid >> 5, o = tid & 31;
    int n0 = blockIdx.x * M1;
    int blkBeg = rowst[n0];
    int blkEnd = (n0 + M1 < N) ? rowst[n0 + M1] : E;
    int total = blkEnd - blkBeg;
    int per = (total + 7) >> 3;
    int wBeg = blkBeg + g * per;
    int wEnd = min(blkEnd, wBeg + per);
    int curDst = -1;
    float acc = 0.0f;
    for (int base = wBeg; base < wEnd; base += 32) {
        int m = min(32, wEnd - base);
        if (o < m) {
            int4 ed = es[base + o];
            eb[g][o] = ed;
            xb[g][o] = x[ed.x];
        }
        for (int jj = 0; jj < m; jj++) {
            int4 ed = eb[g][jj];
            float xs = xb[g][jj];
            int dst = ed.y >> 8;
            if (dst != curDst) {
                if (curDst >= 0) atomicAdd(&agg1[(curDst - n0) * H1C + o], acc);
                acc = 0.0f;
                curDst = dst;
            }
            float f0 = __int_as_float(ed.z), f1 = __int_as_float(ed.w);
            float g0 = 1.0f - f0, g1 = 1.0f - f1;
            int kb = (ed.y & 0xff) << 5;
            float coef = g0 * g1 * w1s[kb + o] + f0 * g1 * w1s[kb + 32 + o] +
                         g0 * f1 * w1s[kb + 160 + o] + f0 * f1 * w1s[kb + 192 + o];
            acc = fmaf(xs, coef, acc);
        }
    }
    if (curDst >= 0) atomicAdd(&agg1[(curDst - n0) * H1C + o], acc);
    __syncthreads();
#pragma unroll
    for (int i = 0; i < 4; i++) {
        int ln = g + 8 * i;
        int n = n0 + ln;
        if (n < N) {
            float rdeg = 1.0f / fmaxf((float)degi[n], 1.0f);
            float hv = fmaxf(agg1[ln * H1C + o] * rdeg + x[n] * root1[o] + b1[o], 0.0f);
            h1[n * H1C + o] = hv;
            h1f[n * H1C + o] = __float2half(hv);
        }
    }
}

// ---------------- xW2 via MFMA: [N][25][64] fp16 = h1f @ W2t ----------------
__global__ __launch_bounds__(256) void xw2m_kernel(
    const __half* __restrict__ h1f,   // [N][32]
    const __half* __restrict__ W2t,   // [25][64][32] (c innermost)
    int N, __half* __restrict__ xph) {  // [N][25][64]
    int wv = threadIdx.x >> 6;
    int lane = threadIdx.x & 63;
    int r15 = lane & 15, quad = lane >> 4;
    int n0 = blockIdx.x * 16;
    int o0 = wv * 16;
    v8h afrag = {};
    int an = n0 + r15;
    if (an < N) afrag = *(const v8h*)(h1f + (size_t)an * H1C + quad * 8);
    for (int k = 0; k < KK; k++) {
        v8h bfrag = *(const v8h*)(W2t + ((k << 6) + o0 + r15) * H1C + quad * 8);
        v4f acc = {};
        acc = __builtin_amdgcn_mfma_f32_16x16x32_f16(afrag, bfrag, acc, 0, 0, 0);
#pragma unroll
        for (int r = 0; r < 4; r++) {
            int mn = n0 + quad * 4 + r;
            if (mn < N)
                xph[(size_t)mn * (KK * H2C) + (k << 6) + o0 + r15] = __float2half(acc[r]);
        }
    }
}

// ---------------- layer 2 scatter: WAVE = ONE EDGE (TLP hides gather latency)
// lane>>5 = tap half j, lane&31 = channel pair. 2 loads + shfl fold + 2 half-
// exec native global atomics into agg2[N][64].
__global__ __launch_bounds__(256) void scatter2_kernel(
    const int4* __restrict__ es,
    const unsigned* __restrict__ xphu,  // [N][25][32] uints (=2 halves)
    int E, float* __restrict__ agg2) {
    int e = (blockIdx.x * 256 + threadIdx.x) >> 6;
    if (e >= E) return;
    int lane = threadIdx.x & 63;
    int j = lane >> 5, o2 = lane & 31;
    int4 ed = es[e];
    const unsigned* p = xphu + (size_t)ed.x * 800 + ((ed.y & 0xff) << 5) + lane;
    unsigned tA = p[0];     // j=0: row kbase   | j=1: row kbase+1
    unsigned tB = p[160];   // j=0: row kbase+5 | j=1: row kbase+6
    float f0 = __int_as_float(ed.z), f1 = __int_as_float(ed.w);
    float blo = j ? f0 : (1.0f - f0);
    float g1v = 1.0f - f1;
    __half2 hA = *(__half2*)&tA, hB = *(__half2*)&tB;
    float vx = blo * fmaf(g1v, __low2float(hA), f1 * __low2float(hB));
    float vy = blo * fmaf(g1v, __high2float(hA), f1 * __high2float(hB));
    vx += __shfl_xor(vx, 32, 64);       // fold j=1 into j=0
    vy += __shfl_xor(vy, 32, 64);
    if (j == 0) {
        int dst = ed.y >> 8;
        atomAddF(&agg2[(size_t)dst * H2C + 2 * o2], vx);
        atomAddF(&agg2[(size_t)dst * H2C + 2 * o2 + 1], vy);
    }
}

// ---------------- fin2: epilogue (root2+relu) + per-graph pool ----------------
__global__ __launch_bounds__(256) void fin2_kernel(
    const float* __restrict__ h1, const float* __restrict__ agg2,
    const int* __restrict__ degi,
    const float* __restrict__ root2, const float* __restrict__ b2,
    const int* __restrict__ batch, int N, float* __restrict__ gsum) {
    __shared__ float h2buf[M2 * H2C];
    int tid = threadIdx.x;
    int w = tid >> 6, lane = tid & 63;
    int n0 = blockIdx.x * M2;
#pragma unroll
    for (int i = 0; i < 4; i++) {
        int ln = w + 4 * i;
        int n = n0 + ln;
        float hv = 0.0f;
        if (n < N) {
            float rd = 1.0f / fmaxf((float)degi[n], 1.0f);
            float v = agg2[(size_t)n * H2C + lane] * rd + b2[lane];
            const float* hr = h1 + n * H1C;
#pragma unroll 8
            for (int c = 0; c < H1C; c++) v = fmaf(hr[c], root2[c * H2C + lane], v);
            hv = fmaxf(v, 0.0f);
        }
        h2buf[ln * H2C + lane] = hv;
    }
    __syncthreads();
    if (tid < H2C) {
        float run = 0.0f;
        int curg = batch[min(n0, N - 1)];
        for (int ln = 0; ln < M2; ln++) {
            int n = n0 + ln;
            if (n >= N) break;
            int gg = batch[n];
            if (gg != curg) {
                atomAddF(&gsum[curg * H2C + tid], run);
                run = 0.0f;
                curg = gg;
            }
            run += h2buf[ln * H2C + tid];
        }
        atomAddF(&gsum[curg * H2C + tid], run);
    }
}

// ---------------- head: count via binary search, FC1+relu, FC2, log_softmax --
__global__ void head_kernel(const float* __restrict__ gsum,
                            const int* __restrict__ batch, int N,
                            const float* __restrict__ Wf1, const float* __restrict__ bf1,
                            const float* __restrict__ Wf2, const float* __restrict__ bf2,
                            float* __restrict__ out) {
    __shared__ float gc[H2C];
    __shared__ float t1[FCC];
    __shared__ float lg[NCLS];
    __shared__ float lse;
    __shared__ float scnt;
    int g = blockIdx.x, tid = threadIdx.x;
    if (tid == 0) {
        int lo = 0, hi = N;
        while (lo < hi) { int m = (lo + hi) >> 1; if (batch[m] < g) lo = m + 1; else hi = m; }
        int lb = lo;
        lo = 0; hi = N;
        while (lo < hi) { int m = (lo + hi) >> 1; if (batch[m] <= g) lo = m + 1; else hi = m; }
        scnt = (float)(lo - lb);
    }
    __syncthreads();
    if (tid < H2C) gc[tid] = gsum[g * H2C + tid] / fmaxf(scnt, 1.0f);
    __syncthreads();
    {
        float acc = bf1[tid];
        for (int c = 0; c < H2C; c++) acc += gc[c] * Wf1[c * FCC + tid];
        t1[tid] = fmaxf(acc, 0.0f);
    }
    __syncthreads();
    if (tid < NCLS) {
        float acc = bf2[tid];
        for (int jj = 0; jj < FCC; jj++) acc += t1[jj] * Wf2[jj * NCLS + tid];
        lg[tid] = acc;
    }
    __syncthreads();
    if (tid == 0) {
        float m = lg[0];
        for (int c = 1; c < NCLS; c++) m = fmaxf(m, lg[c]);
        float s = 0.0f;
        for (int c = 0; c < NCLS; c++) s += expf(lg[c] - m);
        lse = m + logf(s);
    }
    __syncthreads();
    if (tid < NCLS) out[g * NCLS + tid] = lg[tid] - lse;
}

extern "C" void kernel_launch(void* const* d_in, const int* in_sizes, int n_in,
                              void* d_out, int out_size, void* d_ws, size_t ws_size,
                              hipStream_t stream) {
    const float* x          = (const float*)d_in[0];
    const float* edge_attr  = (const float*)d_in[1];
    const float* W1         = (const float*)d_in[2];
    const float* root1      = (const float*)d_in[3];
    const float* b1         = (const float*)d_in[4];
    const float* W2         = (const float*)d_in[5];
    const float* root2      = (const float*)d_in[6];
    const float* b2         = (const float*)d_in[7];
    const float* Wf1        = (const float*)d_in[8];
    const float* bf1        = (const float*)d_in[9];
    const float* Wf2        = (const float*)d_in[10];
    const float* bf2        = (const float*)d_in[11];
    const int*   edge_index = (const int*)d_in[12];
    const int*   batch      = (const int*)d_in[13];
    float* out = (float*)d_out;

    const int N = in_sizes[13];       // 20000
    const int E = in_sizes[12] / 2;   // 320000
    const int NB = (N + 255) / 256;   // scan blocks

    // -------- workspace layout --------
    int4*     es   = (int4*)d_ws;                        // E packed sorted edges
    unsigned* xphu = (unsigned*)(es + E);                // N*800 uints = fp16 [N][25][64]
    __half*   w2t  = (__half*)(xphu + (size_t)N * 800);  // 25*64*32 halves
    __half*   h1f  = w2t + KK * H2C * H1C;               // N*32 halves
    float* gsum  = (float*)(h1f + (size_t)N * H1C);      // NG*H2C  -- zero block start
    float* agg2  = gsum + NG * H2C;                      // N*H2C   -- zero block end
    int*   degi  = (int*)(agg2 + (size_t)N * H2C);       // N
    int*   rowst = degi + N;                             // N
    int*   incl  = rowst + N;                            // N
    int*   bsum  = incl + N;                             // 256
    float* h1    = (float*)(bsum + 256);                 // N*H1C
    int*   part  = (int*)(h1 + (size_t)N * H1C);         // NHB*N (20.5 MB)

    hipMemsetAsync(gsum, 0, (size_t)(NG + N) * H2C * sizeof(float), stream);

    hist_kernel<<<NHB, 256, 0, stream>>>(edge_index, E, N, part);
    merge_kernel<<<NB, 256, 0, stream>>>(part, N, degi);

    scan1_kernel<<<NB, 256, 0, stream>>>(degi, N, incl, bsum);
    scan2_kernel<<<1, 256, 0, stream>>>(bsum, NB);
    scan3_kernel<<<NB, 256, 0, stream>>>(incl, degi, bsum, N, rowst);

    offs_kernel<<<NB, 256, 0, stream>>>(rowst, N, part);
    bucket2_kernel<<<NHB, 256, 0, stream>>>(edge_attr, edge_index, E, N, part, es);

    w2t_kernel<<<(KK * H2C * H1C + 255) / 256, 256, 0, stream>>>(W2, w2t);

    l1_kernel<<<(N + M1 - 1) / M1, 256, 0, stream>>>(
        x, rowst, degi, es, W1, root1, b1, N, E, h1, h1f);

    xw2m_kernel<<<(N + 15) / 16, 256, 0, stream>>>(h1f, w2t, N, (__half*)xphu);

    scatter2_kernel<<<(int)(((size_t)E * 64 + 255) / 256), 256, 0, stream>>>(
        es, xphu, E, agg2);
    fin2_kernel<<<(N + M2 - 1) / M2, 256, 0, stream>>>(
        h1, agg2, degi, root2, b2, batch, N, gsum);

    head_kernel<<<NG, FCC, 0, stream>>>(gsum, batch, N, Wf1, bf1, Wf2, bf2, out);
}

// Round 13
// 255.670 us; speedup vs baseline: 1.6992x; 1.4003x over previous
//
#include <hip/hip_runtime.h>
#include <hip/hip_fp16.h>
#include <math.h>

#define KK 25
#define H1C 32
#define H2C 64
#define FCC 128
#define NCLS 10
#define NG 64
#define M1 32      // nodes per block, layer-1
#define NHB 256    // histogram/bucket blocks
#define HBIN 10240 // LDS histogram bins per pass (40 KB)

typedef _Float16 v8h __attribute__((ext_vector_type(8)));
typedef float v4f __attribute__((ext_vector_type(4)));

__device__ __forceinline__ void atomAddF(float* p, float v) {
    unsafeAtomicAdd(p, v);   // native global_atomic_add_f32
}

// ---------------- degree histogram: per-block LDS bins, int atomics ----------
__global__ __launch_bounds__(256) void hist_kernel(
    const int* __restrict__ edge_index, int E, int N,
    int* __restrict__ part) {            // [NHB][N]
    __shared__ int hs[HBIN];
    int b = blockIdx.x, tid = threadIdx.x;
    int per = (E + NHB - 1) / NHB;
    int beg = b * per, end = min(E, beg + per);
    for (int lo = 0; lo < N; lo += HBIN) {
        int sz = min(HBIN, N - lo);
        __syncthreads();
        for (int i = tid; i < sz; i += 256) hs[i] = 0;
        __syncthreads();
        for (int i = beg + tid; i < end; i += 256) {
            int d = edge_index[E + i] - lo;
            if ((unsigned)d < (unsigned)sz) atomicAdd(&hs[d], 1);
        }
        __syncthreads();
        for (int i = tid; i < sz; i += 256) part[(size_t)b * N + lo + i] = hs[i];
    }
}

__global__ void merge_kernel(const int* __restrict__ part, int N,
                             int* __restrict__ degi) {
    int n = blockIdx.x * 256 + threadIdx.x;
    if (n >= N) return;
    int s = 0;
#pragma unroll 8
    for (int b = 0; b < NHB; b++) s += part[(size_t)b * N + n];
    degi[n] = s;
}

// ---------------- prefix-sum (3-kernel) over degi -> rowst ----------------
__global__ void scan1_kernel(const int* __restrict__ degi, int N,
                             int* __restrict__ incl, int* __restrict__ bsum) {
    __shared__ int s[256];
    int tid = threadIdx.x;
    int i = blockIdx.x * 256 + tid;
    int v = (i < N) ? degi[i] : 0;
    s[tid] = v;
    __syncthreads();
    for (int off = 1; off < 256; off <<= 1) {
        int t = (tid >= off) ? s[tid - off] : 0;
        __syncthreads();
        s[tid] += t;
        __syncthreads();
    }
    if (i < N) incl[i] = s[tid];
    if (tid == 255) bsum[blockIdx.x] = s[255];
}

__global__ void scan2_kernel(int* __restrict__ bsum, int nb) {
    __shared__ int s[256];
    int tid = threadIdx.x;
    int v = (tid < nb) ? bsum[tid] : 0;
    s[tid] = v;
    __syncthreads();
    for (int off = 1; off < 256; off <<= 1) {
        int t = (tid >= off) ? s[tid - off] : 0;
        __syncthreads();
        s[tid] += t;
        __syncthreads();
    }
    if (tid < nb) bsum[tid] = s[tid] - v;   // exclusive
}

__global__ void scan3_kernel(const int* __restrict__ incl, const int* __restrict__ degi,
                             const int* __restrict__ bsum, int N,
                             int* __restrict__ rowst) {
    int i = blockIdx.x * 256 + threadIdx.x;
    if (i >= N) return;
    rowst[i] = incl[i] - degi[i] + bsum[blockIdx.x];
}

// ---------------- offsets: part[b][n] <- rowst[n] + sum_{b'<b} part[b'][n] ----
__global__ void offs_kernel(const int* __restrict__ rowst, int N,
                            int* __restrict__ part) {
    int n = blockIdx.x * 256 + threadIdx.x;
    if (n >= N) return;
    int run = rowst[n];
#pragma unroll 8
    for (int b = 0; b < NHB; b++) {
        int t = part[(size_t)b * N + n];
        part[(size_t)b * N + n] = run;
        run += t;
    }
}

// ---------------- bucket pass 2: place edges via LDS rank counters ----------
__global__ __launch_bounds__(256) void bucket2_kernel(
    const float* __restrict__ edge_attr, const int* __restrict__ edge_index,
    int E, int N, int* __restrict__ part, int4* __restrict__ es) {
    __shared__ int hs[HBIN];
    int b = blockIdx.x, tid = threadIdx.x;
    int per = (E + NHB - 1) / NHB;
    int beg = b * per, end = min(E, beg + per);
    for (int lo = 0; lo < N; lo += HBIN) {
        int sz = min(HBIN, N - lo);
        __syncthreads();
        for (int i = tid; i < sz; i += 256) hs[i] = part[(size_t)b * N + lo + i];
        __syncthreads();
        for (int e = beg + tid; e < end; e += 256) {
            int dst = edge_index[E + e];
            int d = dst - lo;
            if ((unsigned)d < (unsigned)sz) {
                int pos = atomicAdd(&hs[d], 1);          // int ds_add_rtn: rank
                float v0 = edge_attr[2 * e + 0] * 4.0f;
                float v1 = edge_attr[2 * e + 1] * 4.0f;
                int k0 = min(max((int)floorf(v0), 0), 3);
                int k1 = min(max((int)floorf(v1), 0), 3);
                float f0 = v0 - (float)k0, f1 = v1 - (float)k1;
                es[pos] = make_int4(edge_index[e], (dst << 8) | (k0 + 5 * k1),
                                    __float_as_int(f0), __float_as_int(f1));
            }
        }
    }
}

// ---------------- W2 -> fp16 transposed [25][64][32] (c innermost) ----------
__global__ void w2t_kernel(const float* __restrict__ W2, __half* __restrict__ W2t) {
    int idx = blockIdx.x * 256 + threadIdx.x;
    if (idx >= KK * H2C * H1C) return;
    int c = idx & 31, o = (idx >> 5) & 63, k = idx >> 11;
    W2t[idx] = __float2half(W2[(k * H1C + c) * H2C + o]);
}

// ---------------- layer 1: CSR gather, register accumulate (R8 known-good) --
__global__ __launch_bounds__(256) void l1_kernel(
    const float* __restrict__ x,
    const int* __restrict__ rowst, const int* __restrict__ degi,
    const int4* __restrict__ es,
    const float* __restrict__ W1, const float* __restrict__ root1,
    const float* __restrict__ b1, int N, int E,
    float* __restrict__ h1, __half* __restrict__ h1f) {
    __shared__ float w1s[KK * H1C];
    __shared__ float agg1[M1 * H1C];
    __shared__ int4 eb[8][32];
    __shared__ float xb[8][32];
    int tid = threadIdx.x;
    for (int i = tid; i < KK * H1C; i += 256) w1s[i] = W1[i];
    for (int i = tid; i < M1 * H1C; i += 256) agg1[i] = 0.0f;
    __syncthreads();
    int g = tid >> 5, o = tid & 31;
    int n0 = blockIdx.x * M1;
    int blkBeg = rowst[n0];
    int blkEnd = (n0 + M1 < N) ? rowst[n0 + M1] : E;
    int total = blkEnd - blkBeg;
    int per = (total + 7) >> 3;
    int wBeg = blkBeg + g * per;
    int wEnd = min(blkEnd, wBeg + per);
    int curDst = -1;
    float acc = 0.0f;
    for (int base = wBeg; base < wEnd; base += 32) {
        int m = min(32, wEnd - base);
        if (o < m) {
            int4 ed = es[base + o];
            eb[g][o] = ed;
            xb[g][o] = x[ed.x];
        }
        for (int jj = 0; jj < m; jj++) {
            int4 ed = eb[g][jj];
            float xs = xb[g][jj];
            int dst = ed.y >> 8;
            if (dst != curDst) {
                if (curDst >= 0) atomicAdd(&agg1[(curDst - n0) * H1C + o], acc);
                acc = 0.0f;
                curDst = dst;
            }
            float f0 = __int_as_float(ed.z), f1 = __int_as_float(ed.w);
            float g0 = 1.0f - f0, g1 = 1.0f - f1;
            int kb = (ed.y & 0xff) << 5;
            float coef = g0 * g1 * w1s[kb + o] + f0 * g1 * w1s[kb + 32 + o] +
                         g0 * f1 * w1s[kb + 160 + o] + f0 * f1 * w1s[kb + 192 + o];
            acc = fmaf(xs, coef, acc);
        }
    }
    if (curDst >= 0) atomicAdd(&agg1[(curDst - n0) * H1C + o], acc);
    __syncthreads();
#pragma unroll
    for (int i = 0; i < 4; i++) {
        int ln = g + 8 * i;
        int n = n0 + ln;
        if (n < N) {
            float rdeg = 1.0f / fmaxf((float)degi[n], 1.0f);
            float hv = fmaxf(agg1[ln * H1C + o] * rdeg + x[n] * root1[o] + b1[o], 0.0f);
            h1[n * H1C + o] = hv;
            h1f[n * H1C + o] = __float2half(hv);
        }
    }
}

// ---------------- xW2 via MFMA: [N][25][64] fp16 = h1f @ W2t ----------------
__global__ __launch_bounds__(256) void xw2m_kernel(
    const __half* __restrict__ h1f,   // [N][32]
    const __half* __restrict__ W2t,   // [25][64][32] (c innermost)
    int N, __half* __restrict__ xph) {  // [N][25][64]
    int wv = threadIdx.x >> 6;
    int lane = threadIdx.x & 63;
    int r15 = lane & 15, quad = lane >> 4;
    int n0 = blockIdx.x * 16;
    int o0 = wv * 16;
    v8h afrag = {};
    int an = n0 + r15;
    if (an < N) afrag = *(const v8h*)(h1f + (size_t)an * H1C + quad * 8);
    for (int k = 0; k < KK; k++) {
        v8h bfrag = *(const v8h*)(W2t + ((k << 6) + o0 + r15) * H1C + quad * 8);
        v4f acc = {};
        acc = __builtin_amdgcn_mfma_f32_16x16x32_f16(afrag, bfrag, acc, 0, 0, 0);
#pragma unroll
        for (int r = 0; r < 4; r++) {
            int mn = n0 + quad * 4 + r;
            if (mn < N)
                xph[(size_t)mn * (KK * H2C) + (k << 6) + o0 + r15] = __float2half(acc[r]);
        }
    }
}

// ---------------- layer 2 gather: WAVE = ONE NODE, register accumulate ------
// lane>>5 = tap half j, lane&31 = channel pair. 4-edge prefetch batches; no
// atomics: shfl-fold + fused epilogue + plain float2 store to h2.
__global__ __launch_bounds__(256) void l2g_kernel(
    const float* __restrict__ h1,
    const int* __restrict__ rowst, const int* __restrict__ degi,
    const int4* __restrict__ es,
    const unsigned* __restrict__ xphu,  // [N][25][32] uints (=2 halves)
    const float* __restrict__ root2, const float* __restrict__ b2,
    int N, float* __restrict__ h2) {
    int n = blockIdx.x * 4 + (threadIdx.x >> 6);
    if (n >= N) return;
    int lane = threadIdx.x & 63;
    int j = lane >> 5, o2 = lane & 31;
    int beg = rowst[n], cnt = degi[n];
    float ax = 0.0f, ay = 0.0f;
    for (int i0 = 0; i0 < cnt; i0 += 4) {
        int nb = min(4, cnt - i0);
        int4 ed[4];
        unsigned ta[4], tb[4];
#pragma unroll
        for (int t = 0; t < 4; t++) {           // issue all 8 loads first
            int idx = beg + i0 + ((t < nb) ? t : 0);
            ed[t] = es[idx];
            const unsigned* p = xphu + (size_t)ed[t].x * 800 +
                                ((ed[t].y & 0xff) << 5) + lane;
            ta[t] = p[0];     // j=0: row kbase   | j=1: row kbase+1
            tb[t] = p[160];   // j=0: row kbase+5 | j=1: row kbase+6
        }
#pragma unroll
        for (int t = 0; t < 4; t++) {           // consume
            if (t < nb) {
                float f0 = __int_as_float(ed[t].z), f1 = __int_as_float(ed[t].w);
                float blo = j ? f0 : (1.0f - f0);
                float g1v = 1.0f - f1;
                __half2 hA = *(__half2*)&ta[t], hB = *(__half2*)&tb[t];
                ax = fmaf(blo, fmaf(g1v, __low2float(hA), f1 * __low2float(hB)), ax);
                ay = fmaf(blo, fmaf(g1v, __high2float(hA), f1 * __high2float(hB)), ay);
            }
        }
    }
    ax += __shfl_xor(ax, 32, 64);               // fold j=1 half into j=0
    ay += __shfl_xor(ay, 32, 64);
    if (j == 0) {
        float rd = 1.0f / fmaxf((float)cnt, 1.0f);
        float2 bb = *(const float2*)&b2[2 * o2];
        float vx = ax * rd + bb.x;
        float vy = ay * rd + bb.y;
        const float* hr = h1 + n * H1C;
#pragma unroll 8
        for (int c = 0; c < H1C; c++) {
            float2 rt = *(const float2*)&root2[c * H2C + 2 * o2];
            float hc = hr[c];
            vx = fmaf(hc, rt.x, vx);
            vy = fmaf(hc, rt.y, vy);
        }
        float2 hv = make_float2(fmaxf(vx, 0.0f), fmaxf(vy, 0.0f));
        *(float2*)&h2[(size_t)n * H2C + 2 * o2] = hv;
    }
}

// ---------------- pool: block-local per-graph reduction over h2 -------------
__global__ __launch_bounds__(64) void pool_kernel(
    const float* __restrict__ h2, const int* __restrict__ batch,
    int N, float* __restrict__ gsum) {
    int o = threadIdx.x;
    int n0 = blockIdx.x * 16;
    float run = 0.0f;
    int curg = batch[min(n0, N - 1)];
    for (int ln = 0; ln < 16; ln++) {
        int n = n0 + ln;
        if (n >= N) break;
        int gg = batch[n];
        if (gg != curg) {
            atomAddF(&gsum[curg * H2C + o], run);
            run = 0.0f;
            curg = gg;
        }
        run += h2[(size_t)n * H2C + o];
    }
    atomAddF(&gsum[curg * H2C + o], run);
}

// ---------------- head: count via binary search, FC1+relu, FC2, log_softmax --
__global__ void head_kernel(const float* __restrict__ gsum,
                            const int* __restrict__ batch, int N,
                            const float* __restrict__ Wf1, const float* __restrict__ bf1,
                            const float* __restrict__ Wf2, const float* __restrict__ bf2,
                            float* __restrict__ out) {
    __shared__ float gc[H2C];
    __shared__ float t1[FCC];
    __shared__ float lg[NCLS];
    __shared__ float lse;
    __shared__ float scnt;
    int g = blockIdx.x, tid = threadIdx.x;
    if (tid == 0) {
        int lo = 0, hi = N;
        while (lo < hi) { int m = (lo + hi) >> 1; if (batch[m] < g) lo = m + 1; else hi = m; }
        int lb = lo;
        lo = 0; hi = N;
        while (lo < hi) { int m = (lo + hi) >> 1; if (batch[m] <= g) lo = m + 1; else hi = m; }
        scnt = (float)(lo - lb);
    }
    __syncthreads();
    if (tid < H2C) gc[tid] = gsum[g * H2C + tid] / fmaxf(scnt, 1.0f);
    __syncthreads();
    {
        float acc = bf1[tid];
        for (int c = 0; c < H2C; c++) acc += gc[c] * Wf1[c * FCC + tid];
        t1[tid] = fmaxf(acc, 0.0f);
    }
    __syncthreads();
    if (tid < NCLS) {
        float acc = bf2[tid];
        for (int jj = 0; jj < FCC; jj++) acc += t1[jj] * Wf2[jj * NCLS + tid];
        lg[tid] = acc;
    }
    __syncthreads();
    if (tid == 0) {
        float m = lg[0];
        for (int c = 1; c < NCLS; c++) m = fmaxf(m, lg[c]);
        float s = 0.0f;
        for (int c = 0; c < NCLS; c++) s += expf(lg[c] - m);
        lse = m + logf(s);
    }
    __syncthreads();
    if (tid < NCLS) out[g * NCLS + tid] = lg[tid] - lse;
}

extern "C" void kernel_launch(void* const* d_in, const int* in_sizes, int n_in,
                              void* d_out, int out_size, void* d_ws, size_t ws_size,
                              hipStream_t stream) {
    const float* x          = (const float*)d_in[0];
    const float* edge_attr  = (const float*)d_in[1];
    const float* W1         = (const float*)d_in[2];
    const float* root1      = (const float*)d_in[3];
    const float* b1         = (const float*)d_in[4];
    const float* W2         = (const float*)d_in[5];
    const float* root2      = (const float*)d_in[6];
    const float* b2         = (const float*)d_in[7];
    const float* Wf1        = (const float*)d_in[8];
    const float* bf1        = (const float*)d_in[9];
    const float* Wf2        = (const float*)d_in[10];
    const float* bf2        = (const float*)d_in[11];
    const int*   edge_index = (const int*)d_in[12];
    const int*   batch      = (const int*)d_in[13];
    float* out = (float*)d_out;

    const int N = in_sizes[13];       // 20000
    const int E = in_sizes[12] / 2;   // 320000
    const int NB = (N + 255) / 256;   // scan blocks

    // -------- workspace layout --------
    int4*     es   = (int4*)d_ws;                        // E packed sorted edges
    unsigned* xphu = (unsigned*)(es + E);                // N*800 uints = fp16 [N][25][64]
    __half*   w2t  = (__half*)(xphu + (size_t)N * 800);  // 25*64*32 halves
    __half*   h1f  = w2t + KK * H2C * H1C;               // N*32 halves
    float* gsum  = (float*)(h1f + (size_t)N * H1C);      // NG*H2C  -- zeroed
    float* h2    = gsum + NG * H2C;                      // N*H2C
    int*   degi  = (int*)(h2 + (size_t)N * H2C);         // N
    int*   rowst = degi + N;                             // N
    int*   incl  = rowst + N;                            // N
    int*   bsum  = incl + N;                             // 256
    float* h1    = (float*)(bsum + 256);                 // N*H1C
    int*   part  = (int*)(h1 + (size_t)N * H1C);         // NHB*N (20.5 MB)

    hipMemsetAsync(gsum, 0, (size_t)NG * H2C * sizeof(float), stream);

    hist_kernel<<<NHB, 256, 0, stream>>>(edge_index, E, N, part);
    merge_kernel<<<NB, 256, 0, stream>>>(part, N, degi);

    scan1_kernel<<<NB, 256, 0, stream>>>(degi, N, incl, bsum);
    scan2_kernel<<<1, 256, 0, stream>>>(bsum, NB);
    scan3_kernel<<<NB, 256, 0, stream>>>(incl, degi, bsum, N, rowst);

    offs_kernel<<<NB, 256, 0, stream>>>(rowst, N, part);
    bucket2_kernel<<<NHB, 256, 0, stream>>>(edge_attr, edge_index, E, N, part, es);

    w2t_kernel<<<(KK * H2C * H1C + 255) / 256, 256, 0, stream>>>(W2, w2t);

    l1_kernel<<<(N + M1 - 1) / M1, 256, 0, stream>>>(
        x, rowst, degi, es, W1, root1, b1, N, E, h1, h1f);

    xw2m_kernel<<<(N + 15) / 16, 256, 0, stream>>>(h1f, w2t, N, (__half*)xphu);

    l2g_kernel<<<(N + 3) / 4, 256, 0, stream>>>(
        h1, rowst, degi, es, xphu, root2, b2, N, h2);
    pool_kernel<<<(N + 15) / 16, 64, 0, stream>>>(h2, batch, N, gsum);

    head_kernel<<<NG, FCC, 0, stream>>>(gsum, batch, N, Wf1, bf1, Wf2, bf2, out);
}